// Round 6
// baseline (30140.073 us; speedup 1.0000x reference)
//
#include <hip/hip_runtime.h>
#include <hip/hip_bf16.h>

#define DH    64
#define INW   32
#define OUTW  8
#define WIDW  128
#define BATCH 128
#define SEQN  16
#define NSUB  4
#define NT    512

// ---- workspace layout (u32/f32 slots) ----
#define OFF_G8   0         // u32[k4*4096 + e]: 4x fp8 (k=4k4..4k4+3) of gw2 row e
#define OFF_L0F  131072    // u32[k2*128 + o], bf16 pair, 33x128
#define OFF_L0G  135296
#define OFF_L1F  139520    // u32[k2*128 + o], 64x128
#define OFF_L1G  147712
#define OFF_FH   155904    // u32[k2*64 + o], 64x64 (fw2)
#define OFF_RWH  160000    // f32[k*64+o], 64x64
#define OFF_RWX  164096    // f32[k*64+o], 32x64
#define OFF_OW0  166144    // f32[k*128+o], 64x128
#define OFF_OW1  174336    // f32[k*128+o], 128x128
#define OFF_OW2  190720    // f32[k*8+o], 128x8
#define OFF_HP   191744    // f32[b*128 + par*64 + half*32 + r]
#define OFF_FLG  208128    // u32[b*2 + half]
#define WS_TOT   208384

typedef float f32x2 __attribute__((ext_vector_type(2)));

__device__ __forceinline__ float fast_tanh(float x){
  float ax = fabsf(x);
  float e  = __expf(-2.f*ax);
  float r  = __fdividef(1.f - e, 1.f + e);
  return copysignf(r, x);
}
__device__ __forceinline__ float fast_silu(float x){
  return x * __fdividef(1.f, 1.f + __expf(-x));
}
__device__ __forceinline__ uint32_t f2bf(float x){
  uint32_t u = __float_as_uint(x);
  return (u + 0x7fffu + ((u >> 16) & 1u)) >> 16;
}
__device__ __forceinline__ uint32_t f32_to_e4m3fn(float x){
  uint32_t u = __float_as_uint(x);
  uint32_t s = (u >> 31) << 7;
  float ax = fabsf(x);
  uint32_t code;
  if (ax < 0.015625f){
    int m = (int)rintf(ax * 512.0f);
    code = s | (uint32_t)m;
  } else {
    uint32_t bb = (u & 0x7FFFFFFFu) + 0x7FFFFu + ((u >> 20) & 1u);
    uint32_t E  = (bb >> 23) - 120u;
    uint32_t mag = (E << 3) | ((bb >> 20) & 7u);
    if (mag > 0x7Eu) mag = 0x7Eu;
    code = s | mag;
  }
  return code;
}

#if __has_builtin(__builtin_amdgcn_cvt_pk_f32_fp8)
__device__ __forceinline__ f32x2 fp8_lo(uint32_t u){ return __builtin_amdgcn_cvt_pk_f32_fp8(u, false); }
__device__ __forceinline__ f32x2 fp8_hi(uint32_t u){ return __builtin_amdgcn_cvt_pk_f32_fp8(u, true); }
#else
__device__ __forceinline__ float fp8_dec1(uint32_t v){
  uint32_t em = v & 0x7Fu;
  float mag;
  if (em >= 8u) mag = __uint_as_float((em + 960u) << 20);
  else          mag = (float)em * 0.001953125f;
  return (v & 0x80u) ? -mag : mag;
}
__device__ __forceinline__ f32x2 fp8_lo(uint32_t u){ f32x2 r; r[0]=fp8_dec1(u&0xFFu); r[1]=fp8_dec1((u>>8)&0xFFu); return r; }
__device__ __forceinline__ f32x2 fp8_hi(uint32_t u){ f32x2 r; r[0]=fp8_dec1((u>>16)&0xFFu); r[1]=fp8_dec1((u>>24)&0xFFu); return r; }
#endif

__device__ __forceinline__ float bflo(uint32_t u){ return __uint_as_float(u << 16); }
__device__ __forceinline__ float bfhi(uint32_t u){ return __uint_as_float(u & 0xFFFF0000u); }

__global__ void prep(const float* __restrict__ fw0, const float* __restrict__ fw1,
                     const float* __restrict__ fw2, const float* __restrict__ gw0,
                     const float* __restrict__ gw1, const float* __restrict__ gw2,
                     const float* __restrict__ rwh, const float* __restrict__ rwx,
                     const float* __restrict__ ow0, const float* __restrict__ ow1,
                     const float* __restrict__ ow2, uint32_t* __restrict__ wsu)
{
  int i = blockIdx.x * 256 + threadIdx.x;
  if (i >= WS_TOT) return;
  float* wsf = (float*)wsu;
  if (i < OFF_L0F){                      // g8[k4*4096 + e]
    int k4 = i >> 12, e = i & 4095;
    uint32_t u = 0;
    #pragma unroll
    for (int j = 0; j < 4; ++j) u |= f32_to_e4m3fn(gw2[e*128 + 4*k4 + j]) << (8*j);
    wsu[i] = u;
  }
  else if (i < OFF_L0G){ int j=i-OFF_L0F; int k2=j>>7, o=j&127; int k0=2*k2;
    uint32_t lo = f2bf(fw0[o*65+k0]); uint32_t hi = (k0+1<65)? f2bf(fw0[o*65+k0+1]) : 0u;
    wsu[i] = lo | (hi<<16); }
  else if (i < OFF_L1F){ int j=i-OFF_L0G; int k2=j>>7, o=j&127; int k0=2*k2;
    uint32_t lo = f2bf(gw0[o*65+k0]); uint32_t hi = (k0+1<65)? f2bf(gw0[o*65+k0+1]) : 0u;
    wsu[i] = lo | (hi<<16); }
  else if (i < OFF_L1G){ int j=i-OFF_L1F; int k2=j>>7, o=j&127;
    wsu[i] = f2bf(fw1[o*128+2*k2]) | (f2bf(fw1[o*128+2*k2+1])<<16); }
  else if (i < OFF_FH){ int j=i-OFF_L1G; int k2=j>>7, o=j&127;
    wsu[i] = f2bf(gw1[o*128+2*k2]) | (f2bf(gw1[o*128+2*k2+1])<<16); }
  else if (i < OFF_RWH){ int j=i-OFF_FH; int k2=j>>6, o=j&63;
    wsu[i] = f2bf(fw2[o*128+2*k2]) | (f2bf(fw2[o*128+2*k2+1])<<16); }
  else if (i < OFF_RWX){ int j=i-OFF_RWH; int k=j>>6, o=j&63; wsf[i] = rwh[o*64+k]; }
  else if (i < OFF_OW0){ int j=i-OFF_RWX; int k=j>>6, o=j&63; wsf[i] = rwx[o*32+k]; }
  else if (i < OFF_OW1){ int j=i-OFF_OW0; int k=j>>7, o=j&127; wsf[i] = ow0[o*64+k]; }
  else if (i < OFF_OW2){ int j=i-OFF_OW1; int k=j>>7, o=j&127; wsf[i] = ow1[o*128+k]; }
  else if (i < OFF_HP) { int j=i-OFF_OW2; int k=j>>3, o=j&7;  wsf[i] = ow2[o*128+k]; }
  else if (i < OFF_FLG){ wsf[i] = 0.f; }
  else                 { wsu[i] = 0u; }   // flags
}

// NOTE: min-waves/EU = 1 → VGPR cap 512; LDS (118 KB) already limits us to
// 1 block/CU (8 waves), so letting the allocator take ~200 VGPRs for the
// resident g-weights costs zero occupancy. (launch_bounds(512,2) capped at
// 128 VGPR and spilled the weight array to scratch: 38 GB/launch re-fetch.)
__global__ __launch_bounds__(NT, 1) void ace_main(
    const float* __restrict__ ts,
    const float* __restrict__ obs,
    const float* __restrict__ fb0, const float* __restrict__ fb1, const float* __restrict__ fb2,
    const float* __restrict__ gb0, const float* __restrict__ gb1, const float* __restrict__ gb2,
    const float* __restrict__ fsc, const float* __restrict__ gsc,
    const float* __restrict__ rnnb,
    const float* __restrict__ ob0, const float* __restrict__ ob1, const float* __restrict__ ob2,
    uint32_t* __restrict__ wsu,
    float* __restrict__ outp)
{
  constexpr float ATc[5][5] = {
    {0.161f, 0.f, 0.f, 0.f, 0.f},
    {-0.008480655492356989f, 0.335480655492357f, 0.f, 0.f, 0.f},
    {2.8971530571054935f, -6.359448489975075f, 4.3622954328695815f, 0.f, 0.f},
    {5.325864828439257f, -11.748883564062828f, 7.4955393428898365f, -0.09249506636175525f, 0.f},
    {5.86145544294642f, -12.92096931784711f, 8.159367898576159f, -0.071584973281401f, -0.028269050394068383f}};
  constexpr float CTc[6] = {0.f, 0.161f, 0.327f, 0.9f, 0.9800255409045097f, 1.f};
  constexpr float BTc[6] = {0.09646076681806523f, 0.01f, 0.4798896504144996f,
                            1.379008574103742f, -3.290069515436081f, 2.324710524099774f};

  const int tid = threadIdx.x;
  const int bi  = blockIdx.x;
  const int b   = bi & 127;           // batch element
  const int hb  = bi >> 7;            // half: blocks (b, b+128) pair on same XCD (i%8 round-robin)
  const float* wsf = (const float*)wsu;

  const int row  = tid >> 4;          // local row 0..31
  const int grow = hb*32 + row;       // global a-row
  const int c4   = tid & 15;          // col group: cols 4*c4..4*c4+3
  const int e0   = 2048*hb + 4*tid;   // global a-element base (4 rows per thread)

  // ---- LDS ----
  __shared__ uint32_t sL0f[33*128], sL0g[33*128];
  __shared__ uint32_t sL1f[64*128], sL1g[64*128];
  __shared__ uint32_t sFH[64*64];
  __shared__ __align__(16) float h_st[DH], h_b[DH];
  __shared__ __align__(16) float inp[72];
  __shared__ __align__(16) float zf0[WIDW], zg0[WIDW], zf1[WIDW], zg1[WIDW];
  __shared__ float sFB0[WIDW], sGB0[WIDW], sFB1[WIDW], sGB1[WIDW], sFB2[DH];
  __shared__ float red;

  // ---- g-head weights: 4 rows/thread, fp8, RESIDENT IN REGISTERS (128 VGPR) ----
  const uint32_t* g8 = wsu + OFF_G8;
  uint4 wreg[32];
  #pragma unroll
  for (int q = 0; q < 32; ++q) wreg[q] = *(const uint4*)(g8 + q*4096 + e0);

  // ---- fill LDS weight tiles ----
  for (int i = tid; i < 33*128; i += NT){ sL0f[i] = wsu[OFF_L0F + i]; sL0g[i] = wsu[OFF_L0G + i]; }
  for (int i = tid; i < 64*128; i += NT){ sL1f[i] = wsu[OFF_L1F + i]; sL1g[i] = wsu[OFF_L1G + i]; }
  for (int i = tid; i < 64*64;  i += NT){ sFH[i] = wsu[OFF_FH + i]; }
  if (tid < WIDW){ sFB0[tid]=fb0[tid]; sGB0[tid]=gb0[tid]; sFB1[tid]=fb1[tid]; sGB1[tid]=gb1[tid]; }
  if (tid < DH) sFB2[tid] = fb2[tid];

  const float4 gb2v = *(const float4*)&gb2[e0];
  const float sf = fsc[0], sg = gsc[0];

  float a_b[4];
  float ka[6][4];
  float khr[6];              // h-rate history, valid in lane owning o=tid>>2 (p==0, tid<256)
  uint32_t ev = 0;

  float* hp_base = (float*)(wsu + OFF_HP) + b*128;
  uint32_t* flg  = wsu + OFF_FLG + b*2;

  auto attn_from_h = [&](){
    __syncthreads();                     // publish h_b
    if (tid < DH){
      float v = h_b[tid]; v = v*v;
      #pragma unroll
      for (int off = 32; off > 0; off >>= 1) v += __shfl_xor(v, off, 64);
      if (tid == 0) red = __fdividef(1.f, sqrtf(v) + 1e-8f);
      h_st[tid] = h_b[tid];              // next eval's stage state
    }
    __syncthreads();                     // red + h_st visible
    const float inv = red;
    const float hr = h_b[grow] * inv;
    const float4 hc = *(const float4*)&h_b[4*c4];
    a_b[0] = hr * (hc.x * inv);
    a_b[1] = hr * (hc.y * inv);
    a_b[2] = hr * (hc.z * inv);
    a_b[3] = hr * (hc.w * inv);
  };

  // field_eval: stage si (0..5) — produces ka[si]; kh history + h_st/h_b updates
  // are folded into the f-head tail (owning lane registers), so no pre-barrier needed.
  auto field_eval = [&](int si, float dtn, float t, const float (&a_s)[4], float (&ka_out)[4]){
    // ---- softmax over own 32 rows (16-lane groups); reads h_st (covered by prev B5) ----
    {
      float m = fmaxf(fmaxf(a_s[0], a_s[1]), fmaxf(a_s[2], a_s[3]));
      m = fmaxf(m, __shfl_xor(m, 1, 64));
      m = fmaxf(m, __shfl_xor(m, 2, 64));
      m = fmaxf(m, __shfl_xor(m, 4, 64));
      m = fmaxf(m, __shfl_xor(m, 8, 64));
      const float4 hv = *(const float4*)&h_st[4*c4];
      float e0v = __expf(a_s[0]-m), e1v = __expf(a_s[1]-m);
      float e2v = __expf(a_s[2]-m), e3v = __expf(a_s[3]-m);
      float es = (e0v+e1v) + (e2v+e3v);
      float hs = fmaf(e0v,hv.x, fmaf(e1v,hv.y, fmaf(e2v,hv.z, e3v*hv.w)));
      es += __shfl_xor(es, 1, 64); hs += __shfl_xor(hs, 1, 64);
      es += __shfl_xor(es, 2, 64); hs += __shfl_xor(hs, 2, 64);
      es += __shfl_xor(es, 4, 64); hs += __shfl_xor(hs, 4, 64);
      es += __shfl_xor(es, 8, 64); hs += __shfl_xor(hs, 8, 64);
      if (c4 == 0){
        float ip = __fdividef(hs, es);
        inp[grow] = ip;
        __hip_atomic_store(hp_base + (ev & 1)*64 + grow, ip,
                           __ATOMIC_RELAXED, __HIP_MEMORY_SCOPE_AGENT);
      }
      if (tid == 0) inp[DH] = t;
    }
    __syncthreads();                     // B1: hp stores drained
    if (tid == 0)
      __hip_atomic_store(&flg[hb], ev, __ATOMIC_RELEASE, __HIP_MEMORY_SCOPE_AGENT);
    if (tid < 32){
      while (__hip_atomic_load(&flg[1-hb], __ATOMIC_ACQUIRE, __HIP_MEMORY_SCOPE_AGENT) < ev)
        __builtin_amdgcn_s_sleep(1);
      float v = __hip_atomic_load(hp_base + (ev & 1)*64 + (1-hb)*32 + tid,
                                  __ATOMIC_RELAXED, __HIP_MEMORY_SCOPE_AGENT);
      inp[(1-hb)*32 + tid] = v;
    }
    __syncthreads();                     // B2: full inp ready
    // ---- L0: 65 -> 128, f|g halves, split-K p=tid&1 ----
    {
      const bool isf = tid < 256;
      const uint32_t* wL0 = isf ? sL0f : sL0g;
      const int o = (tid >> 1) & 127, p = tid & 1;
      float acc = 0.f;
      #pragma unroll
      for (int kk = 0; kk < 16; ++kk){
        const int k2 = p*16 + kk;
        const uint32_t u = wL0[k2*128 + o];
        acc = fmaf(bflo(u), inp[2*k2], acc);
        acc = fmaf(bfhi(u), inp[2*k2+1], acc);
      }
      if (p == 0) acc = fmaf(bflo(wL0[32*128 + o]), inp[64], acc);
      acc += __shfl_xor(acc, 1, 64);
      if (p == 0) (isf ? zf0 : zg0)[o] = fast_silu(acc + (isf ? sFB0 : sGB0)[o]);
    }
    __syncthreads();                     // B3
    // ---- L1: 128 -> 128 ----
    {
      const bool isf = tid < 256;
      const uint32_t* wL1 = isf ? sL1f : sL1g;
      const float* zi = isf ? zf0 : zg0;
      const int o = (tid >> 1) & 127, p = tid & 1;
      float acc = 0.f;
      #pragma unroll
      for (int kk = 0; kk < 32; ++kk){
        const int k2 = p*32 + kk;
        const uint32_t u = wL1[k2*128 + o];
        acc = fmaf(bflo(u), zi[2*k2], acc);
        acc = fmaf(bfhi(u), zi[2*k2+1], acc);
      }
      acc += __shfl_xor(acc, 1, 64);
      if (p == 0) (isf ? zf1 : zg1)[o] = fast_silu(acc + (isf ? sFB1 : sGB1)[o]);
    }
    __syncthreads();                     // B4
    // ---- f-head (threads 0..255): 128 -> 64; kh + h-state update in owning lane ----
    if (tid < 256){
      const int o = tid >> 2, p = tid & 3;
      float acc = 0.f;
      #pragma unroll
      for (int kk = 0; kk < 16; ++kk){
        const int k2 = p*16 + kk;
        const uint32_t u = sFH[k2*64 + o];
        acc = fmaf(bflo(u), zf1[2*k2], acc);
        acc = fmaf(bfhi(u), zf1[2*k2+1], acc);
      }
      acc += __shfl_xor(acc, 1, 64);
      acc += __shfl_xor(acc, 2, 64);
      if (p == 0){
        khr[si] = sf * fast_tanh(acc + sFB2[o]);
        if (si < 5){
          float s = 0.f;
          #pragma unroll
          for (int j = 0; j <= si; ++j) s = fmaf(ATc[si][j], khr[j], s);
          h_st[o] = fmaf(dtn, s, h_b[o]);      // stage state for eval si+1
        } else {
          float s = 0.f;
          #pragma unroll
          for (int j = 0; j < 6; ++j) s = fmaf(BTc[j], khr[j], s);
          const float hn = fmaf(dtn, s, h_b[o]);
          h_b[o] = hn;                          // substep final combine
          h_st[o] = hn;                         // next substep's eval-0 state
        }
      }
    }
    // ---- g-head: 4 rows/thread, fp8 from REGISTERS, f32x2 (pk) accumulate ----
    {
      f32x2 ac0 = {0.f,0.f}, ac1 = {0.f,0.f}, ac2 = {0.f,0.f}, ac3 = {0.f,0.f};
      const f32x2* zp = (const f32x2*)zg1;
      #pragma unroll
      for (int q = 0; q < 32; ++q){
        const uint4 w = wreg[q];
        const f32x2 z01 = zp[2*q], z23 = zp[2*q+1];
        ac0 = fp8_lo(w.x)*z01 + ac0;  ac0 = fp8_hi(w.x)*z23 + ac0;
        ac1 = fp8_lo(w.y)*z01 + ac1;  ac1 = fp8_hi(w.y)*z23 + ac1;
        ac2 = fp8_lo(w.z)*z01 + ac2;  ac2 = fp8_hi(w.z)*z23 + ac2;
        ac3 = fp8_lo(w.w)*z01 + ac3;  ac3 = fp8_hi(w.w)*z23 + ac3;
      }
      ka_out[0] = sg * fast_tanh(ac0[0] + ac0[1] + gb2v.x);
      ka_out[1] = sg * fast_tanh(ac1[0] + ac1[1] + gb2v.y);
      ka_out[2] = sg * fast_tanh(ac2[0] + ac2[1] + gb2v.z);
      ka_out[3] = sg * fast_tanh(ac3[0] + ac3[1] + gb2v.w);
    }
    __syncthreads();                     // B5: h_st/h_b + buffer reuse
  };

  // ---- init ----
  if (tid < DH){
    float acc = rnnb[tid];
    const float* x0 = obs + b*(SEQN*INW);
    #pragma unroll
    for (int k = 0; k < INW; ++k) acc = fmaf(wsf[OFF_RWX + k*64 + tid], x0[k], acc);
    h_b[tid] = fast_tanh(acc);
  }
  attn_from_h();

  for (int n = 0; n < SEQN-1; ++n){
    const float t0  = ts[b*SEQN + n];
    const float t1  = ts[b*SEQN + n + 1];
    const float dtn = (t1 - t0) * 0.25f;

    for (int isub = 0; isub < NSUB; ++isub){
      const float tb = fmaf((float)isub, dtn, t0);
      ++ev;
      field_eval(0, dtn, tb, a_b, ka[0]);

      #pragma unroll
      for (int s = 0; s < 5; ++s){
        float a_s[4];
        #pragma unroll
        for (int i = 0; i < 4; ++i){
          float acc = 0.f;
          #pragma unroll
          for (int j = 0; j <= s; ++j) acc = fmaf(ATc[s][j], ka[j][i], acc);
          a_s[i] = fmaf(dtn, acc, a_b[i]);
        }
        ++ev;
        field_eval(s+1, dtn, fmaf(CTc[s+1], dtn, tb), a_s, ka[s+1]);
      }

      #pragma unroll
      for (int i = 0; i < 4; ++i){
        float acc = 0.f;
        #pragma unroll
        for (int j = 0; j < 6; ++j) acc = fmaf(BTc[j], ka[j][i], acc);
        a_b[i] = fmaf(dtn, acc, a_b[i]);
      }
    }

    // ---- RNN boundary (h_b current after last eval's B5) ----
    float hnew = 0.f;
    if (tid < DH){
      float acc = rnnb[tid];
      const float* x = obs + (b*SEQN + (n+1))*INW;
      #pragma unroll
      for (int k = 0; k < INW; ++k) acc = fmaf(wsf[OFF_RWX + k*64 + tid], x[k], acc);
      #pragma unroll 8
      for (int k = 0; k < DH; ++k)  acc = fmaf(wsf[OFF_RWH + k*64 + tid], h_b[k], acc);
      hnew = fast_tanh(acc);
    }
    __syncthreads();                 // old h_b reads complete
    if (tid < DH) h_b[tid] = hnew;
    attn_from_h();                   // publishes h_b/red/h_st, computes a_b
  }

  // ---- output MLP (hb==0 block only) ----
  if (hb == 0){
    __syncthreads();
    if (tid < WIDW){
      float acc = ob0[tid];
      #pragma unroll 8
      for (int k = 0; k < DH; ++k) acc = fmaf(wsf[OFF_OW0 + k*128 + tid], h_b[k], acc);
      zf0[tid] = fast_tanh(acc);
    }
    __syncthreads();
    if (tid < WIDW){
      float acc = ob1[tid];
      #pragma unroll 8
      for (int k = 0; k < WIDW; ++k) acc = fmaf(wsf[OFF_OW1 + k*128 + tid], zf0[k], acc);
      zf1[tid] = fast_tanh(acc);
    }
    __syncthreads();
    if (tid < OUTW){
      float acc = ob2[tid];
      #pragma unroll 8
      for (int k = 0; k < WIDW; ++k) acc = fmaf(wsf[OFF_OW2 + k*8 + tid], zf1[k], acc);
      outp[b*OUTW + tid] = acc;
    }
  }
}

extern "C" void kernel_launch(void* const* d_in, const int* in_sizes, int n_in,
                              void* d_out, int out_size, void* d_ws, size_t ws_size,
                              hipStream_t stream)
{
  const float* ts   = (const float*)d_in[0];
  const float* obs  = (const float*)d_in[1];
  const float* fw0  = (const float*)d_in[2];
  const float* fb0  = (const float*)d_in[3];
  const float* fw1  = (const float*)d_in[4];
  const float* fb1  = (const float*)d_in[5];
  const float* fw2  = (const float*)d_in[6];
  const float* fb2  = (const float*)d_in[7];
  const float* gw0  = (const float*)d_in[8];
  const float* gb0  = (const float*)d_in[9];
  const float* gw1  = (const float*)d_in[10];
  const float* gb1  = (const float*)d_in[11];
  const float* gw2  = (const float*)d_in[12];
  const float* gb2  = (const float*)d_in[13];
  const float* fsc  = (const float*)d_in[14];
  const float* gsc  = (const float*)d_in[15];
  const float* rwh  = (const float*)d_in[16];
  const float* rwx  = (const float*)d_in[17];
  const float* rnb  = (const float*)d_in[18];
  const float* ow0  = (const float*)d_in[19];
  const float* ob0  = (const float*)d_in[20];
  const float* ow1  = (const float*)d_in[21];
  const float* ob1  = (const float*)d_in[22];
  const float* ow2  = (const float*)d_in[23];
  const float* ob2  = (const float*)d_in[24];
  uint32_t* wsu = (uint32_t*)d_ws;
  float* outp = (float*)d_out;

  prep<<<(WS_TOT + 255)/256, 256, 0, stream>>>(
      fw0, fw1, fw2, gw0, gw1, gw2, rwh, rwx, ow0, ow1, ow2, wsu);
  ace_main<<<2*BATCH, NT, 0, stream>>>(
      ts, obs, fb0, fb1, fb2, gb0, gb1, gb2, fsc, gsc, rnb, ob0, ob1, ob2, wsu, outp);
}

// Round 7
// 3524.079 us; speedup vs baseline: 8.5526x; 8.5526x over previous
//
#include <hip/hip_runtime.h>
#include <hip/hip_bf16.h>

#define DH    64
#define INW   32
#define OUTW  8
#define WIDW  128
#define BATCH 128
#define SEQN  16
#define NSUB  4
#define NT    1024

// ---- workspace layout (u32/f32 slots) ----
#define OFF_G8   0         // u32[k4*4096 + e]: 4x fp8 (k=4k4..4k4+3) of gw2 row e
#define OFF_L0F  131072    // u32[k2*128 + o], bf16 pair, 33x128
#define OFF_L0G  135296
#define OFF_L1F  139520    // u32[k2*128 + o], 64x128
#define OFF_L1G  147712
#define OFF_FH   155904    // u32[k2*64 + o], 64x64 (fw2)
#define OFF_RWH  160000    // f32[k*64+o], 64x64
#define OFF_RWX  164096    // f32[k*64+o], 32x64
#define OFF_OW0  166144    // f32[k*128+o], 64x128
#define OFF_OW1  174336    // f32[k*128+o], 128x128
#define OFF_OW2  190720    // f32[k*8+o], 128x8
#define WS_TOT   191744

typedef float f32x2 __attribute__((ext_vector_type(2)));

__device__ __forceinline__ float fast_tanh(float x){
  float ax = fabsf(x);
  float e  = __expf(-2.f*ax);
  float r  = __fdividef(1.f - e, 1.f + e);
  return copysignf(r, x);
}
__device__ __forceinline__ float fast_silu(float x){
  return x * __fdividef(1.f, 1.f + __expf(-x));
}
__device__ __forceinline__ uint32_t f2bf(float x){
  uint32_t u = __float_as_uint(x);
  return (u + 0x7fffu + ((u >> 16) & 1u)) >> 16;
}
__device__ __forceinline__ uint32_t f32_to_e4m3fn(float x){
  uint32_t u = __float_as_uint(x);
  uint32_t s = (u >> 31) << 7;
  float ax = fabsf(x);
  uint32_t code;
  if (ax < 0.015625f){
    int m = (int)rintf(ax * 512.0f);
    code = s | (uint32_t)m;
  } else {
    uint32_t bb = (u & 0x7FFFFFFFu) + 0x7FFFFu + ((u >> 20) & 1u);
    uint32_t E  = (bb >> 23) - 120u;
    uint32_t mag = (E << 3) | ((bb >> 20) & 7u);
    if (mag > 0x7Eu) mag = 0x7Eu;
    code = s | mag;
  }
  return code;
}

#if __has_builtin(__builtin_amdgcn_cvt_pk_f32_fp8)
__device__ __forceinline__ f32x2 fp8_lo(uint32_t u){ return __builtin_amdgcn_cvt_pk_f32_fp8(u, false); }
__device__ __forceinline__ f32x2 fp8_hi(uint32_t u){ return __builtin_amdgcn_cvt_pk_f32_fp8(u, true); }
#else
__device__ __forceinline__ float fp8_dec1(uint32_t v){
  uint32_t em = v & 0x7Fu;
  float mag;
  if (em >= 8u) mag = __uint_as_float((em + 960u) << 20);
  else          mag = (float)em * 0.001953125f;
  return (v & 0x80u) ? -mag : mag;
}
__device__ __forceinline__ f32x2 fp8_lo(uint32_t u){ f32x2 r; r[0]=fp8_dec1(u&0xFFu); r[1]=fp8_dec1((u>>8)&0xFFu); return r; }
__device__ __forceinline__ f32x2 fp8_hi(uint32_t u){ f32x2 r; r[0]=fp8_dec1((u>>16)&0xFFu); r[1]=fp8_dec1((u>>24)&0xFFu); return r; }
#endif

__device__ __forceinline__ float bflo(uint32_t u){ return __uint_as_float(u << 16); }
__device__ __forceinline__ float bfhi(uint32_t u){ return __uint_as_float(u & 0xFFFF0000u); }

__global__ void prep(const float* __restrict__ fw0, const float* __restrict__ fw1,
                     const float* __restrict__ fw2, const float* __restrict__ gw0,
                     const float* __restrict__ gw1, const float* __restrict__ gw2,
                     const float* __restrict__ rwh, const float* __restrict__ rwx,
                     const float* __restrict__ ow0, const float* __restrict__ ow1,
                     const float* __restrict__ ow2, uint32_t* __restrict__ wsu)
{
  int i = blockIdx.x * 256 + threadIdx.x;
  if (i >= WS_TOT) return;
  float* wsf = (float*)wsu;
  if (i < OFF_L0F){                      // g8[k4*4096 + e]
    int k4 = i >> 12, e = i & 4095;
    uint32_t u = 0;
    #pragma unroll
    for (int j = 0; j < 4; ++j) u |= f32_to_e4m3fn(gw2[e*128 + 4*k4 + j]) << (8*j);
    wsu[i] = u;
  }
  else if (i < OFF_L0G){ int j=i-OFF_L0F; int k2=j>>7, o=j&127; int k0=2*k2;
    uint32_t lo = f2bf(fw0[o*65+k0]); uint32_t hi = (k0+1<65)? f2bf(fw0[o*65+k0+1]) : 0u;
    wsu[i] = lo | (hi<<16); }
  else if (i < OFF_L1F){ int j=i-OFF_L0G; int k2=j>>7, o=j&127; int k0=2*k2;
    uint32_t lo = f2bf(gw0[o*65+k0]); uint32_t hi = (k0+1<65)? f2bf(gw0[o*65+k0+1]) : 0u;
    wsu[i] = lo | (hi<<16); }
  else if (i < OFF_L1G){ int j=i-OFF_L1F; int k2=j>>7, o=j&127;
    wsu[i] = f2bf(fw1[o*128+2*k2]) | (f2bf(fw1[o*128+2*k2+1])<<16); }
  else if (i < OFF_FH){ int j=i-OFF_L1G; int k2=j>>7, o=j&127;
    wsu[i] = f2bf(gw1[o*128+2*k2]) | (f2bf(gw1[o*128+2*k2+1])<<16); }
  else if (i < OFF_RWH){ int j=i-OFF_FH; int k2=j>>6, o=j&63;
    wsu[i] = f2bf(fw2[o*128+2*k2]) | (f2bf(fw2[o*128+2*k2+1])<<16); }
  else if (i < OFF_RWX){ int j=i-OFF_RWH; int k=j>>6, o=j&63; wsf[i] = rwh[o*64+k]; }
  else if (i < OFF_OW0){ int j=i-OFF_RWX; int k=j>>6, o=j&63; wsf[i] = rwx[o*32+k]; }
  else if (i < OFF_OW1){ int j=i-OFF_OW0; int k=j>>7, o=j&127; wsf[i] = ow0[o*64+k]; }
  else if (i < OFF_OW2){ int j=i-OFF_OW1; int k=j>>7, o=j&127; wsf[i] = ow1[o*128+k]; }
  else                 { int j=i-OFF_OW2; int k=j>>3, o=j&7;  wsf[i] = ow2[o*128+k]; }
}

// 1024 threads = 16 waves/block, LDS ~122KB -> 1 block/CU, 4 waves/SIMD.
// launch_bounds(1024,4): 4 waves/EU min -> VGPR cap 128 (required for 16-wave
// residency). One block per batch element: NO inter-block handshake.
__global__ __launch_bounds__(NT, 4) void ace_main(
    const float* __restrict__ ts,
    const float* __restrict__ obs,
    const float* __restrict__ fb0, const float* __restrict__ fb1, const float* __restrict__ fb2,
    const float* __restrict__ gb0, const float* __restrict__ gb1, const float* __restrict__ gb2,
    const float* __restrict__ fsc, const float* __restrict__ gsc,
    const float* __restrict__ rnnb,
    const float* __restrict__ ob0, const float* __restrict__ ob1, const float* __restrict__ ob2,
    uint32_t* __restrict__ wsu,
    float* __restrict__ outp)
{
  constexpr float ATc[5][5] = {
    {0.161f, 0.f, 0.f, 0.f, 0.f},
    {-0.008480655492356989f, 0.335480655492357f, 0.f, 0.f, 0.f},
    {2.8971530571054935f, -6.359448489975075f, 4.3622954328695815f, 0.f, 0.f},
    {5.325864828439257f, -11.748883564062828f, 7.4955393428898365f, -0.09249506636175525f, 0.f},
    {5.86145544294642f, -12.92096931784711f, 8.159367898576159f, -0.071584973281401f, -0.028269050394068383f}};
  constexpr float CTc[6] = {0.f, 0.161f, 0.327f, 0.9f, 0.9800255409045097f, 1.f};
  constexpr float BTc[6] = {0.09646076681806523f, 0.01f, 0.4798896504144996f,
                            1.379008574103742f, -3.290069515436081f, 2.324710524099774f};

  const int tid = threadIdx.x;
  const int b   = blockIdx.x;
  const float* wsf = (const float*)wsu;

  const int row = tid >> 4;        // a-row 0..63
  const int c4  = tid & 15;        // col group: cols 4*c4..4*c4+3
  const int e0  = 4*tid;           // a-element base (4 per thread)

  // ---- LDS (trunk bf16, padded strides 129/65 -> <=2-way bank aliasing) ----
  __shared__ uint32_t sL0f[33*129], sL0g[33*129];
  __shared__ uint32_t sL1f[64*129], sL1g[64*129];
  __shared__ uint32_t sFH[64*65];
  __shared__ __align__(16) float h_st[DH], h_b[DH];
  __shared__ __align__(16) float inp[72];
  __shared__ __align__(16) float zf0[WIDW], zg0[WIDW], zf1[WIDW], zg1[WIDW];
  __shared__ float sFB0[WIDW], sGB0[WIDW], sFB1[WIDW], sGB1[WIDW], sFB2[DH];
  __shared__ float red;

  for (int i = tid; i < 33*128; i += NT){
    int k2 = i >> 7, o = i & 127; int d = k2*129 + o;
    sL0f[d] = wsu[OFF_L0F + i]; sL0g[d] = wsu[OFF_L0G + i];
  }
  for (int i = tid; i < 64*128; i += NT){
    int k2 = i >> 7, o = i & 127; int d = k2*129 + o;
    sL1f[d] = wsu[OFF_L1F + i]; sL1g[d] = wsu[OFF_L1G + i];
  }
  for (int i = tid; i < 64*64; i += NT){
    int k2 = i >> 6, o = i & 63;
    sFH[k2*65 + o] = wsu[OFF_FH + i];
  }
  if (tid < WIDW){ sFB0[tid]=fb0[tid]; sGB0[tid]=gb0[tid]; sFB1[tid]=fb1[tid]; sGB1[tid]=gb1[tid]; }
  if (tid < DH) sFB2[tid] = fb2[tid];

  const uint32_t* g8 = wsu + OFF_G8;
  const float4 gb2v = *(const float4*)&gb2[e0];
  const float sf = fsc[0], sg = gsc[0];

  float a_b[4];
  float ka[6][4];
  float khr[6];      // valid in FH owning lanes (tid<512, (tid&7)==0)

  auto attn_from_h = [&](){
    __syncthreads();                 // publish h_b
    if (tid < DH){
      float v = h_b[tid]; v = v*v;
      #pragma unroll
      for (int off = 32; off > 0; off >>= 1) v += __shfl_xor(v, off, 64);
      if (tid == 0) red = __fdividef(1.f, sqrtf(v) + 1e-8f);
      h_st[tid] = h_b[tid];          // next eval's stage state
    }
    __syncthreads();                 // red + h_st visible
    const float inv = red;
    const float hr = h_b[row] * inv;
    const float4 hc = *(const float4*)&h_b[4*c4];
    a_b[0] = hr * (hc.x * inv);
    a_b[1] = hr * (hc.y * inv);
    a_b[2] = hr * (hc.z * inv);
    a_b[3] = hr * (hc.w * inv);
  };

  // field_eval stage si: produces ka[si]; kh history + h_st/h_b fold in FH tail.
  auto field_eval = [&](int si, float dtn, float t, const float (&a_s)[4], float (&ka_out)[4]){
    // ---- softmax rows (16-lane groups); h_st covered by prev barrier ----
    {
      float m = fmaxf(fmaxf(a_s[0], a_s[1]), fmaxf(a_s[2], a_s[3]));
      m = fmaxf(m, __shfl_xor(m, 1, 64));
      m = fmaxf(m, __shfl_xor(m, 2, 64));
      m = fmaxf(m, __shfl_xor(m, 4, 64));
      m = fmaxf(m, __shfl_xor(m, 8, 64));
      const float4 hv = *(const float4*)&h_st[4*c4];
      float e0v = __expf(a_s[0]-m), e1v = __expf(a_s[1]-m);
      float e2v = __expf(a_s[2]-m), e3v = __expf(a_s[3]-m);
      float es = (e0v+e1v) + (e2v+e3v);
      float hs = fmaf(e0v,hv.x, fmaf(e1v,hv.y, fmaf(e2v,hv.z, e3v*hv.w)));
      es += __shfl_xor(es, 1, 64); hs += __shfl_xor(hs, 1, 64);
      es += __shfl_xor(es, 2, 64); hs += __shfl_xor(hs, 2, 64);
      es += __shfl_xor(es, 4, 64); hs += __shfl_xor(hs, 4, 64);
      es += __shfl_xor(es, 8, 64); hs += __shfl_xor(hs, 8, 64);
      if (c4 == 0) inp[row] = __fdividef(hs, es);
      if (tid == 0) inp[DH] = t;
    }
    __syncthreads();                     // B1: inp ready
    // ---- L0: 65 -> 128, f: tid<512, g: tid>=512; 4-way split-K ----
    {
      const bool isf = tid < 512;
      const uint32_t* wL0 = isf ? sL0f : sL0g;
      const int o = (tid >> 2) & 127, p = tid & 3;
      float acc = 0.f;
      #pragma unroll
      for (int j = 0; j < 8; ++j){
        const int k2 = p*8 + j;
        const uint32_t u = wL0[k2*129 + o];
        const f32x2 z = *(const f32x2*)&inp[2*k2];
        acc = fmaf(bflo(u), z[0], acc);
        acc = fmaf(bfhi(u), z[1], acc);
      }
      if (p == 0) acc = fmaf(bflo(wL0[32*129 + o]), inp[64], acc);
      acc += __shfl_xor(acc, 1, 64);
      acc += __shfl_xor(acc, 2, 64);
      if (p == 0) (isf ? zf0 : zg0)[o] = fast_silu(acc + (isf ? sFB0 : sGB0)[o]);
    }
    __syncthreads();                     // B2
    // ---- L1: 128 -> 128 ----
    {
      const bool isf = tid < 512;
      const uint32_t* wL1 = isf ? sL1f : sL1g;
      const float* zi = isf ? zf0 : zg0;
      const int o = (tid >> 2) & 127, p = tid & 3;
      float acc = 0.f;
      #pragma unroll
      for (int j = 0; j < 16; ++j){
        const int k2 = p*16 + j;
        const uint32_t u = wL1[k2*129 + o];
        const f32x2 z = *(const f32x2*)&zi[2*k2];
        acc = fmaf(bflo(u), z[0], acc);
        acc = fmaf(bfhi(u), z[1], acc);
      }
      acc += __shfl_xor(acc, 1, 64);
      acc += __shfl_xor(acc, 2, 64);
      if (p == 0) (isf ? zf1 : zg1)[o] = fast_silu(acc + (isf ? sFB1 : sGB1)[o]);
    }
    __syncthreads();                     // B3
    // ---- f-head (tid<512): 128 -> 64, 8-way split-K; h fold in owning lane ----
    if (tid < 512){
      const int o = tid >> 3, p = tid & 7;
      float acc = 0.f;
      #pragma unroll
      for (int j = 0; j < 8; ++j){
        const int k2 = p*8 + j;
        const uint32_t u = sFH[k2*65 + o];
        const f32x2 z = *(const f32x2*)&zf1[2*k2];
        acc = fmaf(bflo(u), z[0], acc);
        acc = fmaf(bfhi(u), z[1], acc);
      }
      acc += __shfl_xor(acc, 1, 64);
      acc += __shfl_xor(acc, 2, 64);
      acc += __shfl_xor(acc, 4, 64);
      if (p == 0){
        khr[si] = sf * fast_tanh(acc + sFB2[o]);
        if (si < 5){
          float s = 0.f;
          #pragma unroll
          for (int j = 0; j <= si; ++j) s = fmaf(ATc[si][j], khr[j], s);
          h_st[o] = fmaf(dtn, s, h_b[o]);     // stage state for eval si+1
        } else {
          float s = 0.f;
          #pragma unroll
          for (int j = 0; j < 6; ++j) s = fmaf(BTc[j], khr[j], s);
          const float hn = fmaf(dtn, s, h_b[o]);
          h_b[o] = hn;                         // substep final combine
          h_st[o] = hn;                        // next substep's eval-0 state
        }
      }
    }
    // ---- g-head: 4 rows/thread, fp8 streamed from L2, pk-fma accumulate ----
    {
      f32x2 ac0 = {0.f,0.f}, ac1 = {0.f,0.f}, ac2 = {0.f,0.f}, ac3 = {0.f,0.f};
      #pragma unroll 8
      for (int k4 = 0; k4 < 32; ++k4){
        const uint4 w = *(const uint4*)(g8 + k4*4096 + e0);
        const float4 zz = *(const float4*)&zg1[4*k4];
        const f32x2 z01 = {zz.x, zz.y}, z23 = {zz.z, zz.w};
        ac0 = fp8_lo(w.x)*z01 + ac0;  ac0 = fp8_hi(w.x)*z23 + ac0;
        ac1 = fp8_lo(w.y)*z01 + ac1;  ac1 = fp8_hi(w.y)*z23 + ac1;
        ac2 = fp8_lo(w.z)*z01 + ac2;  ac2 = fp8_hi(w.z)*z23 + ac2;
        ac3 = fp8_lo(w.w)*z01 + ac3;  ac3 = fp8_hi(w.w)*z23 + ac3;
      }
      ka_out[0] = sg * fast_tanh(ac0[0] + ac0[1] + gb2v.x);
      ka_out[1] = sg * fast_tanh(ac1[0] + ac1[1] + gb2v.y);
      ka_out[2] = sg * fast_tanh(ac2[0] + ac2[1] + gb2v.z);
      ka_out[3] = sg * fast_tanh(ac3[0] + ac3[1] + gb2v.w);
    }
    __syncthreads();                     // B4: h_st/h_b + buffer reuse
  };

  // ---- init: h0 = tanh(rwx @ obs[0] + b); a0 = attn(h0) ----
  if (tid < DH){
    float acc = rnnb[tid];
    const float* x0 = obs + b*(SEQN*INW);
    #pragma unroll
    for (int k = 0; k < INW; ++k) acc = fmaf(wsf[OFF_RWX + k*64 + tid], x0[k], acc);
    h_b[tid] = fast_tanh(acc);
  }
  attn_from_h();

  for (int n = 0; n < SEQN-1; ++n){
    const float t0  = ts[b*SEQN + n];
    const float t1  = ts[b*SEQN + n + 1];
    const float dtn = (t1 - t0) * 0.25f;

    for (int isub = 0; isub < NSUB; ++isub){
      const float tb = fmaf((float)isub, dtn, t0);
      field_eval(0, dtn, tb, a_b, ka[0]);

      #pragma unroll
      for (int s = 0; s < 5; ++s){
        float a_s[4];
        #pragma unroll
        for (int i = 0; i < 4; ++i){
          float acc = 0.f;
          #pragma unroll
          for (int j = 0; j <= s; ++j) acc = fmaf(ATc[s][j], ka[j][i], acc);
          a_s[i] = fmaf(dtn, acc, a_b[i]);
        }
        field_eval(s+1, dtn, fmaf(CTc[s+1], dtn, tb), a_s, ka[s+1]);
      }

      #pragma unroll
      for (int i = 0; i < 4; ++i){
        float acc = 0.f;
        #pragma unroll
        for (int j = 0; j < 6; ++j) acc = fmaf(BTc[j], ka[j][i], acc);
        a_b[i] = fmaf(dtn, acc, a_b[i]);
      }
    }

    // ---- RNN boundary: h <- tanh(Wh h' + Wx x + b); a <- attn(h) ----
    float hnew = 0.f;
    if (tid < DH){
      float acc = rnnb[tid];
      const float* x = obs + (b*SEQN + (n+1))*INW;
      #pragma unroll
      for (int k = 0; k < INW; ++k) acc = fmaf(wsf[OFF_RWX + k*64 + tid], x[k], acc);
      #pragma unroll 8
      for (int k = 0; k < DH; ++k)  acc = fmaf(wsf[OFF_RWH + k*64 + tid], h_b[k], acc);
      hnew = fast_tanh(acc);
    }
    __syncthreads();                 // old h_b reads complete
    if (tid < DH) h_b[tid] = hnew;
    attn_from_h();                   // publishes h_b/red/h_st, computes a_b
  }

  // ---- output MLP (tanh) ----
  __syncthreads();
  if (tid < WIDW){
    float acc = ob0[tid];
    #pragma unroll 8
    for (int k = 0; k < DH; ++k) acc = fmaf(wsf[OFF_OW0 + k*128 + tid], h_b[k], acc);
    zf0[tid] = fast_tanh(acc);
  }
  __syncthreads();
  if (tid < WIDW){
    float acc = ob1[tid];
    #pragma unroll 8
    for (int k = 0; k < WIDW; ++k) acc = fmaf(wsf[OFF_OW1 + k*128 + tid], zf0[k], acc);
    zf1[tid] = fast_tanh(acc);
  }
  __syncthreads();
  if (tid < OUTW){
    float acc = ob2[tid];
    #pragma unroll 8
    for (int k = 0; k < WIDW; ++k) acc = fmaf(wsf[OFF_OW2 + k*8 + tid], zf1[k], acc);
    outp[b*OUTW + tid] = acc;
  }
}

extern "C" void kernel_launch(void* const* d_in, const int* in_sizes, int n_in,
                              void* d_out, int out_size, void* d_ws, size_t ws_size,
                              hipStream_t stream)
{
  const float* ts   = (const float*)d_in[0];
  const float* obs  = (const float*)d_in[1];
  const float* fw0  = (const float*)d_in[2];
  const float* fb0  = (const float*)d_in[3];
  const float* fw1  = (const float*)d_in[4];
  const float* fb1  = (const float*)d_in[5];
  const float* fw2  = (const float*)d_in[6];
  const float* fb2  = (const float*)d_in[7];
  const float* gw0  = (const float*)d_in[8];
  const float* gb0  = (const float*)d_in[9];
  const float* gw1  = (const float*)d_in[10];
  const float* gb1  = (const float*)d_in[11];
  const float* gw2  = (const float*)d_in[12];
  const float* gb2  = (const float*)d_in[13];
  const float* fsc  = (const float*)d_in[14];
  const float* gsc  = (const float*)d_in[15];
  const float* rwh  = (const float*)d_in[16];
  const float* rwx  = (const float*)d_in[17];
  const float* rnb  = (const float*)d_in[18];
  const float* ow0  = (const float*)d_in[19];
  const float* ob0  = (const float*)d_in[20];
  const float* ow1  = (const float*)d_in[21];
  const float* ob1  = (const float*)d_in[22];
  const float* ow2  = (const float*)d_in[23];
  const float* ob2  = (const float*)d_in[24];
  uint32_t* wsu = (uint32_t*)d_ws;
  float* outp = (float*)d_out;

  prep<<<(WS_TOT + 255)/256, 256, 0, stream>>>(
      fw0, fw1, fw2, gw0, gw1, gw2, rwh, rwx, ow0, ow1, ow2, wsu);
  ace_main<<<BATCH, NT, 0, stream>>>(
      ts, obs, fb0, fb1, fb2, gb0, gb1, gb2, fsc, gsc, rnb, ob0, ob1, ob2, wsu, outp);
}